// Round 23
// baseline (287.762 us; speedup 1.0000x reference)
//
#include <hip/hip_runtime.h>
#include <hip/hip_bf16.h>

// CognitiveWorkspace — ONE fused kernel, INTRA-BLOCK wave specialization.
// 512 threads = 8 waves; 1024 blocks x 16 tokens.
//   waves 0-3 (GATE): tag-mean -> gin; query=H*Wq^T (direct-global frags,
//     barrier-free); bar; Wg MFMA -> gtile; bar; epilogue (hub + gate_out).
//   waves 4-7 (STREAM): all 6 non-hub columns (8-deep batches), then 2 bars.
// Gate latency is covered by co-resident stream waves on the same CU (m114).
// Single writer per element; no d_out reads.

#define DM 2048      // d_model
#define DSZ 6656     // D_S
#define HUBOFF 4608  // hub_shared offset (floats)
#define TAGOFF 5120
#define NTOK 16384   // B*T
#define DHS 512      // d_hub_shared

typedef __attribute__((ext_vector_type(8))) short bf16x8;
typedef __attribute__((ext_vector_type(4))) float f32x4;

__device__ __forceinline__ float sigmoidf_(float x) {
  return 1.0f / (1.0f + __expf(-x));
}
__device__ __forceinline__ short f2bf(float x) {
  return (short)__bfloat16_as_ushort(__float2bfloat16(x));
}
__device__ __forceinline__ bf16x8 cvt8(float4 a, float4 b) {
  bf16x8 r;
  r[0] = f2bf(a.x); r[1] = f2bf(a.y); r[2] = f2bf(a.z); r[3] = f2bf(a.w);
  r[4] = f2bf(b.x); r[5] = f2bf(b.y); r[6] = f2bf(b.z); r[7] = f2bf(b.w);
  return r;
}
#define MFMA(a, b, c) __builtin_amdgcn_mfma_f32_16x16x32_bf16((a), (b), (c), 0, 0, 0)

__global__ __launch_bounds__(512) void cw_fused_kernel(
    const float* __restrict__ S, const float* __restrict__ H,
    const float* __restrict__ Wq, const float* __restrict__ Wg,
    const float* __restrict__ bg, const float* __restrict__ whs,
    const float* __restrict__ w_spoke, const float* __restrict__ w_hub_priv,
    const float* __restrict__ tgin, const int* __restrict__ lip,
    float* __restrict__ outS, float* __restrict__ gate_out)
{
  __shared__ float gin[16][132];    // 8.4 KB
  __shared__ float gtile[16][516];  // 33 KB

  const int tid = threadIdx.x;
  const int li = *lip;
  const int start = (li > 8) ? (li - 8) : 0;
  const int ntags = li - start;
  const float tscale = (ntags > 0) ? (1.0f / (float)ntags) : 0.0f;
  const int trs = TAGOFF + start * 64;
  const int tok0 = blockIdx.x * 16;
  const int w = tid >> 6;              // wave 0..7
  const int l = tid & 63, l15 = l & 15, l4 = l >> 4;

  const int sp0 = li * 32;             // spoke add (quads)
  const int hp0 = 768 + li * 16;       // hub_priv add
  const int tg0 = 1280 + li * 16;      // tag add

  const float4* S4 = reinterpret_cast<const float4*>(S);
  const float4* SP4 = reinterpret_cast<const float4*>(w_spoke);
  const float4* HP4 = reinterpret_cast<const float4*>(w_hub_priv);
  const float4* TG4 = reinterpret_cast<const float4*>(tgin);
  float4* O4 = reinterpret_cast<float4*>(outS);

  if (w >= 4) {
    // ================= STREAM waves: all 6 non-hub columns =================
    const int stid = tid - 256;                       // 0..255
    for (int j = 0; j < 6; ++j) {
      const int c = j * 256 + stid;                   // 0..1535
      const int cp = c + ((c >= 1152) ? 128 : 0);     // skip hub quads
#pragma unroll
      for (int half = 0; half < 2; ++half) {
        float4 sv[8];
#pragma unroll
        for (int k = 0; k < 8; ++k)
          sv[k] = S4[(size_t)(tok0 + half * 8 + k) * 1664u + cp];
#pragma unroll
        for (int k = 0; k < 8; ++k) {
          const int r = half * 8 + k;
          float4 o = sv[k];
          if (cp >= sp0 && cp < sp0 + 32) {
            float4 v = SP4[(size_t)(tok0 + r) * 32u + (cp - sp0)];
            o.x += v.x; o.y += v.y; o.z += v.z; o.w += v.w;
          } else if (cp >= hp0 && cp < hp0 + 16) {
            float4 v = HP4[(size_t)(tok0 + r) * 16u + (cp - hp0)];
            o.x += v.x; o.y += v.y; o.z += v.z; o.w += v.w;
          } else if (cp >= tg0 && cp < tg0 + 16) {
            float4 v = TG4[(size_t)(tok0 + r) * 16u + (cp - tg0)];
            o.x += v.x; o.y += v.y; o.z += v.z; o.w += v.w;
          }
          O4[(size_t)(tok0 + r) * 1664u + cp] = o;
        }
      }
    }
    __syncthreads();   // match gate barrier 1
    __syncthreads();   // match gate barrier 2
  } else {
    // ================= GATE waves (0..3, tid 0..255) =================
    // ph1: tag-mean direct from S -> gin[tok][64..127]
    {
      const int tk = tid >> 4, t16 = tid & 15;
      const float4* sp =
          reinterpret_cast<const float4*>(S + (size_t)(tok0 + tk) * DSZ + trs) + t16;
      float4 acc = {0.f, 0.f, 0.f, 0.f};
      for (int g = 0; g < ntags; ++g) {
        float4 v = sp[g * 16];
        acc.x += v.x; acc.y += v.y; acc.z += v.z; acc.w += v.w;
      }
      const int d = 64 + t16 * 4;
      gin[tk][d + 0] = acc.x * tscale;
      gin[tk][d + 1] = acc.y * tscale;
      gin[tk][d + 2] = acc.z * tscale;
      gin[tk][d + 3] = acc.w * tscale;
    }

    // ph2: query = H*Wq^T; wave w = q-tile w; direct-global fragments,
    // barrier-free (R15 form) — latency covered by stream waves.
    const int q0 = w * 16;
    {
      const float* ha = H + (size_t)(tok0 + l15) * DM + l4 * 8;
      const float* wq = Wq + (size_t)(q0 + l15) * DM + l4 * 8;
      f32x4 qacc = {0.f, 0.f, 0.f, 0.f};
#pragma unroll 4
      for (int ks = 0; ks < 64; ++ks) {
        float4 a0 = *reinterpret_cast<const float4*>(ha + ks * 32);
        float4 a1 = *reinterpret_cast<const float4*>(ha + ks * 32 + 4);
        float4 b0 = *reinterpret_cast<const float4*>(wq + ks * 32);
        float4 b1 = *reinterpret_cast<const float4*>(wq + ks * 32 + 4);
        qacc = MFMA(cvt8(a0, a1), cvt8(b0, b1), qacc);
      }
#pragma unroll
      for (int i = 0; i < 4; ++i)
        gin[l4 * 4 + i][q0 + l15] = qacc[i];
    }
    __syncthreads();   // barrier 1: gin complete

    // ph3: Wg MFMA -> gtile
    bf16x8 afr[4];
#pragma unroll
    for (int ks = 0; ks < 4; ++ks) {
      const float* p = &gin[l15][ks * 32 + l4 * 8];
      afr[ks] = cvt8(*reinterpret_cast<const float4*>(p),
                     *reinterpret_cast<const float4*>(p + 4));
    }
    const float* wgb = Wg + (size_t)l15 * 128 + l4 * 8;
    for (int jp = 0; jp < 4; ++jp) {
      const int ht0 = w * 8 + jp * 2;
      const float* wp0 = wgb + (size_t)ht0 * 16 * 128;
      const float* wp1 = wp0 + 16 * 128;
      float4 r0[4][2], r1[4][2];
#pragma unroll
      for (int ks = 0; ks < 4; ++ks) {
        r0[ks][0] = *reinterpret_cast<const float4*>(wp0 + ks * 32);
        r0[ks][1] = *reinterpret_cast<const float4*>(wp0 + ks * 32 + 4);
        r1[ks][0] = *reinterpret_cast<const float4*>(wp1 + ks * 32);
        r1[ks][1] = *reinterpret_cast<const float4*>(wp1 + ks * 32 + 4);
      }
      f32x4 accA = {0.f,0.f,0.f,0.f}, accB = {0.f,0.f,0.f,0.f};
#pragma unroll
      for (int ks = 0; ks < 4; ++ks) {
        accA = MFMA(afr[ks], cvt8(r0[ks][0], r0[ks][1]), accA);
        accB = MFMA(afr[ks], cvt8(r1[ks][0], r1[ks][1]), accB);
      }
#pragma unroll
      for (int t = 0; t < 2; ++t) {
        const f32x4 a = t ? accB : accA;
        const int h = (ht0 + t) * 16 + l15;
        const float bgv = bg[h];
#pragma unroll
        for (int i = 0; i < 4; ++i)
          gtile[l4 * 4 + i][h] = sigmoidf_(a[i] + bgv);
      }
    }
    __syncthreads();   // barrier 2: gtile complete

    // epilogue: out_hub = S_hub * g + whs; gate_out = g (coalesced)
#pragma unroll
    for (int r2 = 0; r2 < 8; ++r2) {
      const int idx = r2 * 256 + tid;
      const int row = idx >> 7, qq = idx & 127;
      const int tok = tok0 + row;
      float4 g = *reinterpret_cast<const float4*>(&gtile[row][qq * 4]);
      float4 s = *reinterpret_cast<const float4*>(S + (size_t)tok * DSZ + HUBOFF + qq * 4);
      float4 wv = *reinterpret_cast<const float4*>(whs + (size_t)tok * DHS + qq * 4);
      float4 o;
      o.x = s.x * g.x + wv.x;
      o.y = s.y * g.y + wv.y;
      o.z = s.z * g.z + wv.z;
      o.w = s.w * g.w + wv.w;
      *reinterpret_cast<float4*>(outS + (size_t)tok * DSZ + HUBOFF + qq * 4) = o;
      *reinterpret_cast<float4*>(gate_out + (size_t)tok * DHS + qq * 4) = g;
    }
  }
}

extern "C" void kernel_launch(void* const* d_in, const int* in_sizes, int n_in,
                              void* d_out, int out_size, void* d_ws, size_t ws_size,
                              hipStream_t stream) {
  (void)in_sizes; (void)n_in; (void)out_size; (void)d_ws; (void)ws_size;
  const float* S            = (const float*)d_in[0];
  const float* H            = (const float*)d_in[1];
  const float* w_spoke      = (const float*)d_in[2];
  const float* w_hub_priv   = (const float*)d_in[3];
  const float* w_hub_shared = (const float*)d_in[4];
  const float* tgin         = (const float*)d_in[5];
  const float* Wq           = (const float*)d_in[6];
  const float* Wg           = (const float*)d_in[7];
  const float* bg           = (const float*)d_in[8];
  const int*   lip          = (const int*)d_in[9];

  float* outS = (float*)d_out;
  float* gate_out = outS + (size_t)NTOK * DSZ;

  cw_fused_kernel<<<1024, 512, 0, stream>>>(
      S, H, Wq, Wg, bg, w_hub_shared, w_spoke, w_hub_priv, tgin, lip,
      outS, gate_out);
}

// Round 25
// 240.407 us; speedup vs baseline: 1.1970x; 1.1970x over previous
//
#include <hip/hip_runtime.h>
#include <hip/hip_bf16.h>

// CognitiveWorkspace — ONE fused kernel, de-phased block roles (R20 base +
// nontemporal hints). bid&1 parity => whole-XCD role segregation.
// NT stores on outS/gate_out (write-once), NT loads on single-use inputs
// (w_spoke/w_hub_priv/tgin/whs) => L2/L3 reserved for S/H/Wq/Wg reuse.
// NT accesses go through clang ext_vector f32x4 (builtin rejects float4).
// STREAM: non-hub 1536 quads/row of 16 rows, adds inline, 8-deep batches.
// GATE  : tag-mean (direct S), query=H*Wq^T (H LDS-staged), Wg MFMA,
//         epilogue: out_hub = S_hub*g + whs; gate_out = g.
// LDS 42 KB -> 3 blocks/CU.

#define DM 2048      // d_model
#define DSZ 6656     // D_S
#define HUBOFF 4608  // hub_shared offset (floats)
#define TAGOFF 5120
#define NTOK 16384   // B*T
#define DHS 512      // d_hub_shared
#define HSTRIDE 1048 // H-stage LDS row stride (bf16)

typedef __attribute__((ext_vector_type(8))) short bf16x8;
typedef __attribute__((ext_vector_type(4))) short s16x4;
typedef __attribute__((ext_vector_type(4))) float f32x4;

__device__ __forceinline__ float sigmoidf_(float x) {
  return 1.0f / (1.0f + __expf(-x));
}
__device__ __forceinline__ short f2bf(float x) {
  return (short)__bfloat16_as_ushort(__float2bfloat16(x));
}
__device__ __forceinline__ bf16x8 cvt8(float4 a, float4 b) {
  bf16x8 r;
  r[0] = f2bf(a.x); r[1] = f2bf(a.y); r[2] = f2bf(a.z); r[3] = f2bf(a.w);
  r[4] = f2bf(b.x); r[5] = f2bf(b.y); r[6] = f2bf(b.z); r[7] = f2bf(b.w);
  return r;
}
// nontemporal helpers via ext_vector (builtin rejects HIP_vector_type)
__device__ __forceinline__ f32x4 nt_load4(const float* p) {
  return __builtin_nontemporal_load(reinterpret_cast<const f32x4*>(p));
}
__device__ __forceinline__ void nt_store4(float* p, f32x4 v) {
  __builtin_nontemporal_store(v, reinterpret_cast<f32x4*>(p));
}
#define MFMA(a, b, c) __builtin_amdgcn_mfma_f32_16x16x32_bf16((a), (b), (c), 0, 0, 0)

__global__ __launch_bounds__(256) void cw_fused_kernel(
    const float* __restrict__ S, const float* __restrict__ H,
    const float* __restrict__ Wq, const float* __restrict__ Wg,
    const float* __restrict__ bg, const float* __restrict__ whs,
    const float* __restrict__ w_spoke, const float* __restrict__ w_hub_priv,
    const float* __restrict__ tgin, const int* __restrict__ lip,
    float* __restrict__ outS, float* __restrict__ gate_out)
{
  __shared__ float gin[16][132];                        // 8.4 KB
  __shared__ __align__(16) char smem[16 * HSTRIDE * 2]; // 33.5 KB union:
  short (*hds)[HSTRIDE] = (short (*)[HSTRIDE])smem;     //   H-stage (bf16)
  float (*gtile)[516]   = (float (*)[516])smem;         //   gate tile (fp32)

  const int tid = threadIdx.x;
  const int li = *lip;
  const int start = (li > 8) ? (li - 8) : 0;
  const int ntags = li - start;
  const float tscale = (ntags > 0) ? (1.0f / (float)ntags) : 0.0f;
  const int trs = TAGOFF + start * 64;
  const int tok0 = blockIdx.x * 16;
  const int w = tid >> 6, l = tid & 63, l15 = l & 15, l4 = l >> 4;

  const int sp0 = li * 32;           // spoke add (quads)
  const int hp0 = 768 + li * 16;     // hub_priv add
  const int tg0 = 1280 + li * 16;    // tag add

  const float4* S4 = reinterpret_cast<const float4*>(S);
  float4* O4 = reinterpret_cast<float4*>(outS);

  // ------------- STREAM: non-hub quads, adds inline, 8-deep -------------
  auto STREAM = [&]() {
    for (int j = 0; j < 6; ++j) {
      const int c = j * 256 + tid;                    // 0..1535
      const int cp = c + ((c >= 1152) ? 128 : 0);     // skip hub quads
#pragma unroll
      for (int half = 0; half < 2; ++half) {
        float4 sv[8];
#pragma unroll
        for (int k = 0; k < 8; ++k)
          sv[k] = S4[(size_t)(tok0 + half * 8 + k) * 1664u + cp];
#pragma unroll
        for (int k = 0; k < 8; ++k) {
          const int r = half * 8 + k;
          f32x4 o = {sv[k].x, sv[k].y, sv[k].z, sv[k].w};
          if (cp >= sp0 && cp < sp0 + 32) {
            f32x4 v = nt_load4(w_spoke + ((size_t)(tok0 + r) * 32u + (cp - sp0)) * 4);
            o += v;
          } else if (cp >= hp0 && cp < hp0 + 16) {
            f32x4 v = nt_load4(w_hub_priv + ((size_t)(tok0 + r) * 16u + (cp - hp0)) * 4);
            o += v;
          } else if (cp >= tg0 && cp < tg0 + 16) {
            f32x4 v = nt_load4(tgin + ((size_t)(tok0 + r) * 16u + (cp - tg0)) * 4);
            o += v;
          }
          nt_store4(outS + ((size_t)(tok0 + r) * 1664u + cp) * 4, o);
        }
      }
    }
  };

  // ---------------- GATE: mean/query/Wg/epilogue ----------------
  auto GATE = [&]() {
    // ph1: tag-mean direct from S -> gin[tok][64..127]
    {
      const int tk = tid >> 4, t16 = tid & 15;
      const float4* sp =
          reinterpret_cast<const float4*>(S + (size_t)(tok0 + tk) * DSZ + trs) + t16;
      float4 acc = {0.f, 0.f, 0.f, 0.f};
      for (int g = 0; g < ntags; ++g) {
        float4 v = sp[g * 16];
        acc.x += v.x; acc.y += v.y; acc.z += v.z; acc.w += v.w;
      }
      const int d = 64 + t16 * 4;
      gin[tk][d + 0] = acc.x * tscale;
      gin[tk][d + 1] = acc.y * tscale;
      gin[tk][d + 2] = acc.z * tscale;
      gin[tk][d + 3] = acc.w * tscale;
    }

    // ph2: query = H*Wq^T over 2 K-chunks; H staged contiguous into LDS
    const int q0 = w * 16;
    f32x4 qacc = {0.f, 0.f, 0.f, 0.f};
    for (int kc = 0; kc < 2; ++kc) {
      float4 st[16];
      const float* hb = H + (size_t)(tok0 + w * 4) * DM + kc * 1024;
#pragma unroll
      for (int j = 0; j < 16; ++j)
        st[j] = *reinterpret_cast<const float4*>(
            hb + (size_t)(j >> 2) * DM + (j & 3) * 256 + l * 4);
      __syncthreads();                 // prior chunk's LDS reads complete
#pragma unroll
      for (int j = 0; j < 16; ++j) {
        s16x4 v;
        v[0] = f2bf(st[j].x); v[1] = f2bf(st[j].y);
        v[2] = f2bf(st[j].z); v[3] = f2bf(st[j].w);
        *reinterpret_cast<s16x4*>(&hds[w * 4 + (j >> 2)][(j & 3) * 256 + l * 4]) = v;
      }
      __syncthreads();
      const float* wqb = Wq + (size_t)(q0 + l15) * DM + kc * 1024 + l4 * 8;
#pragma unroll 4
      for (int ks = 0; ks < 32; ++ks) {
        bf16x8 af = *reinterpret_cast<const bf16x8*>(&hds[l15][ks * 32 + l4 * 8]);
        float4 b0 = *reinterpret_cast<const float4*>(wqb + ks * 32);
        float4 b1 = *reinterpret_cast<const float4*>(wqb + ks * 32 + 4);
        qacc = MFMA(af, cvt8(b0, b1), qacc);
      }
    }
#pragma unroll
    for (int i = 0; i < 4; ++i)
      gin[l4 * 4 + i][q0 + l15] = qacc[i];
    __syncthreads();   // gin complete; hds reads done (gtile reuses smem)

    // ph3: Wg MFMA -> gtile
    bf16x8 afr[4];
#pragma unroll
    for (int ks = 0; ks < 4; ++ks) {
      const float* p = &gin[l15][ks * 32 + l4 * 8];
      afr[ks] = cvt8(*reinterpret_cast<const float4*>(p),
                     *reinterpret_cast<const float4*>(p + 4));
    }
    const float* wgb = Wg + (size_t)l15 * 128 + l4 * 8;
    for (int jp = 0; jp < 4; ++jp) {
      const int ht0 = w * 8 + jp * 2;
      const float* wp0 = wgb + (size_t)ht0 * 16 * 128;
      const float* wp1 = wp0 + 16 * 128;
      float4 r0[4][2], r1[4][2];
#pragma unroll
      for (int ks = 0; ks < 4; ++ks) {
        r0[ks][0] = *reinterpret_cast<const float4*>(wp0 + ks * 32);
        r0[ks][1] = *reinterpret_cast<const float4*>(wp0 + ks * 32 + 4);
        r1[ks][0] = *reinterpret_cast<const float4*>(wp1 + ks * 32);
        r1[ks][1] = *reinterpret_cast<const float4*>(wp1 + ks * 32 + 4);
      }
      f32x4 accA = {0.f,0.f,0.f,0.f}, accB = {0.f,0.f,0.f,0.f};
#pragma unroll
      for (int ks = 0; ks < 4; ++ks) {
        accA = MFMA(afr[ks], cvt8(r0[ks][0], r0[ks][1]), accA);
        accB = MFMA(afr[ks], cvt8(r1[ks][0], r1[ks][1]), accB);
      }
#pragma unroll
      for (int t = 0; t < 2; ++t) {
        const f32x4 a = t ? accB : accA;
        const int h = (ht0 + t) * 16 + l15;
        const float bgv = bg[h];
#pragma unroll
        for (int i = 0; i < 4; ++i)
          gtile[l4 * 4 + i][h] = sigmoidf_(a[i] + bgv);
      }
    }
    __syncthreads();

    // epilogue: out_hub = S_hub * g + whs; gate_out = g (coalesced, NT out)
#pragma unroll
    for (int r2 = 0; r2 < 8; ++r2) {
      const int idx = r2 * 256 + tid;
      const int row = idx >> 7, qq = idx & 127;
      const int tok = tok0 + row;
      const float* gp = &gtile[row][qq * 4];
      f32x4 g = {gp[0], gp[1], gp[2], gp[3]};
      float4 s = *reinterpret_cast<const float4*>(S + (size_t)tok * DSZ + HUBOFF + qq * 4);
      f32x4 sv = {s.x, s.y, s.z, s.w};
      f32x4 wv = nt_load4(whs + (size_t)tok * DHS + qq * 4);
      f32x4 o = sv * g + wv;
      nt_store4(outS + (size_t)tok * DSZ + HUBOFF + qq * 4, o);
      nt_store4(gate_out + (size_t)tok * DHS + qq * 4, g);
    }
  };

  // ---- de-phase (R17/R20-proven parity)
  if (blockIdx.x & 1) { GATE(); STREAM(); }
  else                { STREAM(); GATE(); }
}

extern "C" void kernel_launch(void* const* d_in, const int* in_sizes, int n_in,
                              void* d_out, int out_size, void* d_ws, size_t ws_size,
                              hipStream_t stream) {
  (void)in_sizes; (void)n_in; (void)out_size; (void)d_ws; (void)ws_size;
  const float* S            = (const float*)d_in[0];
  const float* H            = (const float*)d_in[1];
  const float* w_spoke      = (const float*)d_in[2];
  const float* w_hub_priv   = (const float*)d_in[3];
  const float* w_hub_shared = (const float*)d_in[4];
  const float* tgin         = (const float*)d_in[5];
  const float* Wq           = (const float*)d_in[6];
  const float* Wg           = (const float*)d_in[7];
  const float* bg           = (const float*)d_in[8];
  const int*   lip          = (const int*)d_in[9];

  float* outS = (float*)d_out;
  float* gate_out = outS + (size_t)NTOK * DSZ;

  cw_fused_kernel<<<1024, 256, 0, stream>>>(
      S, H, Wq, Wg, bg, w_hub_shared, w_spoke, w_hub_priv, tgin, lip,
      outS, gate_out);
}

// Round 26
// 239.861 us; speedup vs baseline: 1.1997x; 1.0023x over previous
//
#include <hip/hip_runtime.h>
#include <hip/hip_bf16.h>

// CognitiveWorkspace — ONE fused kernel, de-phased block roles (R25 base +
// LDS shrink 42->25 KB for 6 blocks/CU residency).
// bid&1 parity => whole-XCD role segregation. NT stores/loads as R25.
// ph2 stages H in 4 chunks of 512 floats (hds 16.6 KB); gtile is bf16 and
// unions with hds (lifetime-disjoint, barrier-separated).
// STREAM: non-hub 1536 quads/row of 16 rows, adds inline, 8-deep batches.

#define DM 2048      // d_model
#define DSZ 6656     // D_S
#define HUBOFF 4608  // hub_shared offset (floats)
#define TAGOFF 5120
#define NTOK 16384   // B*T
#define DHS 512      // d_hub_shared
#define HSTRIDE 520  // H-stage LDS row stride in bf16 (512 + 8 pad)

typedef __attribute__((ext_vector_type(8))) short bf16x8;
typedef __attribute__((ext_vector_type(4))) short s16x4;
typedef __attribute__((ext_vector_type(4))) float f32x4;

__device__ __forceinline__ float sigmoidf_(float x) {
  return 1.0f / (1.0f + __expf(-x));
}
__device__ __forceinline__ short f2bf(float x) {
  return (short)__bfloat16_as_ushort(__float2bfloat16(x));
}
__device__ __forceinline__ float bf2f(short x) {
  return __builtin_bit_cast(float, (unsigned)((unsigned short)x) << 16);
}
__device__ __forceinline__ bf16x8 cvt8(float4 a, float4 b) {
  bf16x8 r;
  r[0] = f2bf(a.x); r[1] = f2bf(a.y); r[2] = f2bf(a.z); r[3] = f2bf(a.w);
  r[4] = f2bf(b.x); r[5] = f2bf(b.y); r[6] = f2bf(b.z); r[7] = f2bf(b.w);
  return r;
}
__device__ __forceinline__ f32x4 nt_load4(const float* p) {
  return __builtin_nontemporal_load(reinterpret_cast<const f32x4*>(p));
}
__device__ __forceinline__ void nt_store4(float* p, f32x4 v) {
  __builtin_nontemporal_store(v, reinterpret_cast<f32x4*>(p));
}
#define MFMA(a, b, c) __builtin_amdgcn_mfma_f32_16x16x32_bf16((a), (b), (c), 0, 0, 0)

__global__ __launch_bounds__(256) void cw_fused_kernel(
    const float* __restrict__ S, const float* __restrict__ H,
    const float* __restrict__ Wq, const float* __restrict__ Wg,
    const float* __restrict__ bg, const float* __restrict__ whs,
    const float* __restrict__ w_spoke, const float* __restrict__ w_hub_priv,
    const float* __restrict__ tgin, const int* __restrict__ lip,
    float* __restrict__ outS, float* __restrict__ gate_out)
{
  __shared__ float gin[16][132];                    // 8.4 KB
  __shared__ __align__(16) short ubuf[16][HSTRIDE]; // 16.6 KB union:
  // ph2: H-stage chunk (bf16, 512 k-values); ph3+: gate tile (bf16, 512 h)

  const int tid = threadIdx.x;
  const int li = *lip;
  const int start = (li > 8) ? (li - 8) : 0;
  const int ntags = li - start;
  const float tscale = (ntags > 0) ? (1.0f / (float)ntags) : 0.0f;
  const int trs = TAGOFF + start * 64;
  const int tok0 = blockIdx.x * 16;
  const int w = tid >> 6, l = tid & 63, l15 = l & 15, l4 = l >> 4;

  const int sp0 = li * 32;           // spoke add (quads)
  const int hp0 = 768 + li * 16;     // hub_priv add
  const int tg0 = 1280 + li * 16;    // tag add

  const float4* S4 = reinterpret_cast<const float4*>(S);

  // ------------- STREAM: non-hub quads, adds inline, 8-deep -------------
  auto STREAM = [&]() {
    for (int j = 0; j < 6; ++j) {
      const int c = j * 256 + tid;                    // 0..1535
      const int cp = c + ((c >= 1152) ? 128 : 0);     // skip hub quads
#pragma unroll
      for (int half = 0; half < 2; ++half) {
        float4 sv[8];
#pragma unroll
        for (int k = 0; k < 8; ++k)
          sv[k] = S4[(size_t)(tok0 + half * 8 + k) * 1664u + cp];
#pragma unroll
        for (int k = 0; k < 8; ++k) {
          const int r = half * 8 + k;
          f32x4 o = {sv[k].x, sv[k].y, sv[k].z, sv[k].w};
          if (cp >= sp0 && cp < sp0 + 32) {
            o += nt_load4(w_spoke + ((size_t)(tok0 + r) * 32u + (cp - sp0)) * 4);
          } else if (cp >= hp0 && cp < hp0 + 16) {
            o += nt_load4(w_hub_priv + ((size_t)(tok0 + r) * 16u + (cp - hp0)) * 4);
          } else if (cp >= tg0 && cp < tg0 + 16) {
            o += nt_load4(tgin + ((size_t)(tok0 + r) * 16u + (cp - tg0)) * 4);
          }
          nt_store4(outS + ((size_t)(tok0 + r) * 1664u + cp) * 4, o);
        }
      }
    }
  };

  // ---------------- GATE: mean/query/Wg/epilogue ----------------
  auto GATE = [&]() {
    // ph1: tag-mean direct from S -> gin[tok][64..127]
    {
      const int tk = tid >> 4, t16 = tid & 15;
      const float4* sp =
          reinterpret_cast<const float4*>(S + (size_t)(tok0 + tk) * DSZ + trs) + t16;
      float4 acc = {0.f, 0.f, 0.f, 0.f};
      for (int g = 0; g < ntags; ++g) {
        float4 v = sp[g * 16];
        acc.x += v.x; acc.y += v.y; acc.z += v.z; acc.w += v.w;
      }
      const int d = 64 + t16 * 4;
      gin[tk][d + 0] = acc.x * tscale;
      gin[tk][d + 1] = acc.y * tscale;
      gin[tk][d + 2] = acc.z * tscale;
      gin[tk][d + 3] = acc.w * tscale;
    }

    // ph2: query = H*Wq^T over 4 K-chunks of 512; H staged into ubuf (bf16)
    const int q0 = w * 16;
    f32x4 qacc = {0.f, 0.f, 0.f, 0.f};
    for (int kc = 0; kc < 4; ++kc) {
      float4 st[8];
      // wave w loads rows 4w..4w+3, 512 floats each = 2 segs of 256
      const float* hb = H + (size_t)(tok0 + w * 4) * DM + kc * 512;
#pragma unroll
      for (int j = 0; j < 8; ++j)
        st[j] = *reinterpret_cast<const float4*>(
            hb + (size_t)(j >> 1) * DM + (j & 1) * 256 + l * 4);
      __syncthreads();                 // prior chunk's LDS reads complete
#pragma unroll
      for (int j = 0; j < 8; ++j) {
        s16x4 v;
        v[0] = f2bf(st[j].x); v[1] = f2bf(st[j].y);
        v[2] = f2bf(st[j].z); v[3] = f2bf(st[j].w);
        *reinterpret_cast<s16x4*>(&ubuf[w * 4 + (j >> 1)][(j & 1) * 256 + l * 4]) = v;
      }
      __syncthreads();
      const float* wqb = Wq + (size_t)(q0 + l15) * DM + kc * 512 + l4 * 8;
#pragma unroll 4
      for (int ks = 0; ks < 16; ++ks) {
        bf16x8 af = *reinterpret_cast<const bf16x8*>(&ubuf[l15][ks * 32 + l4 * 8]);
        float4 b0 = *reinterpret_cast<const float4*>(wqb + ks * 32);
        float4 b1 = *reinterpret_cast<const float4*>(wqb + ks * 32 + 4);
        qacc = MFMA(af, cvt8(b0, b1), qacc);
      }
    }
#pragma unroll
    for (int i = 0; i < 4; ++i)
      gin[l4 * 4 + i][q0 + l15] = qacc[i];
    __syncthreads();   // gin complete; all ubuf(H) reads done (gtile reuses)

    // ph3: Wg MFMA -> ubuf as bf16 gate tile
    bf16x8 afr[4];
#pragma unroll
    for (int ks = 0; ks < 4; ++ks) {
      const float* p = &gin[l15][ks * 32 + l4 * 8];
      afr[ks] = cvt8(*reinterpret_cast<const float4*>(p),
                     *reinterpret_cast<const float4*>(p + 4));
    }
    const float* wgb = Wg + (size_t)l15 * 128 + l4 * 8;
    for (int jp = 0; jp < 4; ++jp) {
      const int ht0 = w * 8 + jp * 2;
      const float* wp0 = wgb + (size_t)ht0 * 16 * 128;
      const float* wp1 = wp0 + 16 * 128;
      float4 r0[4][2], r1[4][2];
#pragma unroll
      for (int ks = 0; ks < 4; ++ks) {
        r0[ks][0] = *reinterpret_cast<const float4*>(wp0 + ks * 32);
        r0[ks][1] = *reinterpret_cast<const float4*>(wp0 + ks * 32 + 4);
        r1[ks][0] = *reinterpret_cast<const float4*>(wp1 + ks * 32);
        r1[ks][1] = *reinterpret_cast<const float4*>(wp1 + ks * 32 + 4);
      }
      f32x4 accA = {0.f,0.f,0.f,0.f}, accB = {0.f,0.f,0.f,0.f};
#pragma unroll
      for (int ks = 0; ks < 4; ++ks) {
        accA = MFMA(afr[ks], cvt8(r0[ks][0], r0[ks][1]), accA);
        accB = MFMA(afr[ks], cvt8(r1[ks][0], r1[ks][1]), accB);
      }
#pragma unroll
      for (int t = 0; t < 2; ++t) {
        const f32x4 a = t ? accB : accA;
        const int h = (ht0 + t) * 16 + l15;
        const float bgv = bg[h];
#pragma unroll
        for (int i = 0; i < 4; ++i)
          ubuf[l4 * 4 + i][h] = f2bf(sigmoidf_(a[i] + bgv));
      }
    }
    __syncthreads();

    // epilogue: out_hub = S_hub * g + whs; gate_out = g (coalesced, NT out)
#pragma unroll
    for (int r2 = 0; r2 < 8; ++r2) {
      const int idx = r2 * 256 + tid;
      const int row = idx >> 7, qq = idx & 127;
      const int tok = tok0 + row;
      s16x4 gh = *reinterpret_cast<const s16x4*>(&ubuf[row][qq * 4]);
      f32x4 g = {bf2f(gh[0]), bf2f(gh[1]), bf2f(gh[2]), bf2f(gh[3])};
      float4 s = *reinterpret_cast<const float4*>(S + (size_t)tok * DSZ + HUBOFF + qq * 4);
      f32x4 sv = {s.x, s.y, s.z, s.w};
      f32x4 wv = nt_load4(whs + (size_t)tok * DHS + qq * 4);
      f32x4 o = sv * g + wv;
      nt_store4(outS + (size_t)tok * DSZ + HUBOFF + qq * 4, o);
      nt_store4(gate_out + (size_t)tok * DHS + qq * 4, g);
    }
  };

  // ---- de-phase (R17/R20/R25-proven parity)
  if (blockIdx.x & 1) { GATE(); STREAM(); }
  else                { STREAM(); GATE(); }
}

extern "C" void kernel_launch(void* const* d_in, const int* in_sizes, int n_in,
                              void* d_out, int out_size, void* d_ws, size_t ws_size,
                              hipStream_t stream) {
  (void)in_sizes; (void)n_in; (void)out_size; (void)d_ws; (void)ws_size;
  const float* S            = (const float*)d_in[0];
  const float* H            = (const float*)d_in[1];
  const float* w_spoke      = (const float*)d_in[2];
  const float* w_hub_priv   = (const float*)d_in[3];
  const float* w_hub_shared = (const float*)d_in[4];
  const float* tgin         = (const float*)d_in[5];
  const float* Wq           = (const float*)d_in[6];
  const float* Wg           = (const float*)d_in[7];
  const float* bg           = (const float*)d_in[8];
  const int*   lip          = (const int*)d_in[9];

  float* outS = (float*)d_out;
  float* gate_out = outS + (size_t)NTOK * DSZ;

  cw_fused_kernel<<<1024, 256, 0, stream>>>(
      S, H, Wq, Wg, bg, w_hub_shared, w_spoke, w_hub_priv, tgin, lip,
      outS, gate_out);
}